// Round 1
// baseline (213.832 us; speedup 1.0000x reference)
//
#include <hip/hip_runtime.h>
#include <stdint.h>

// Dims: msa[1,S,R,M] fp32 ; left_w/right_w[M,C] ; out_w[C*C,CZ] ; out[1,R,R,CZ] fp32
#define S_DIM 128
#define R_DIM 256
#define M_DIM 256
#define C_DIM 32
#define CZ_DIM 128
#define K2_DIM 1024  // C*C

typedef _Float16 f16;
typedef _Float16 f16x8 __attribute__((ext_vector_type(8)));
typedef float f32x4 __attribute__((ext_vector_type(4)));

// ---------------------------------------------------------------------------
// prep: weights -> f16, transposed so MFMA operand loads are k-contiguous.
//   wt_l/wt_r[c][m]  (A-operand for proj:   A[row=c][k=m])
//   wt_o[cz][k2]     (B-operand for stage2: B^T[n=cz][k=k2])
// ---------------------------------------------------------------------------
__global__ void prep_kernel(const float* __restrict__ lw, const float* __restrict__ rw,
                            const float* __restrict__ ow,
                            f16* __restrict__ wt_l, f16* __restrict__ wt_r,
                            f16* __restrict__ wt_o) {
    int idx = blockIdx.x * blockDim.x + threadIdx.x;
    int stride = gridDim.x * blockDim.x;
    for (int i = idx; i < CZ_DIM * K2_DIM; i += stride) {
        int cz = i >> 10, k2 = i & 1023;
        wt_o[i] = (f16)ow[k2 * CZ_DIM + cz];
    }
    for (int i = idx; i < C_DIM * M_DIM; i += stride) {
        int c = i >> 8, m = i & 255;
        wt_l[i] = (f16)lw[m * C_DIM + c];
        wt_r[i] = (f16)rw[m * C_DIM + c];
    }
}

// ---------------------------------------------------------------------------
// proj: per block (r, s-half): D = wt(32xC rows x 256 k) @ msa_r^T (256 x 64 s)
// for both weights. Writes left_t[(r*32+c)][s], right_t likewise (f16).
// These layouts are exactly the A/B operand layouts stage-1 needs (k=s contig).
// ---------------------------------------------------------------------------
__global__ __launch_bounds__(256, 2)
void proj_kernel(const float* __restrict__ msa, const f16* __restrict__ wt_l,
                 const f16* __restrict__ wt_r,
                 f16* __restrict__ left_t, f16* __restrict__ right_t) {
    int bid = blockIdx.x;            // 512 = 256 r * 2 s-halves
    int r  = bid >> 1;
    int s0 = (bid & 1) << 6;         // 0 or 64
    int tid = threadIdx.x;
    int w = tid >> 6;                // wave 0..3 -> 16-wide s subtile
    int lane = tid & 63;
    int q = lane >> 4, li = lane & 15;

    int s_col = s0 + w * 16 + li;    // this lane's s (MFMA n index)
    const float* bsrc = msa + ((size_t)s_col * R_DIM + r) * M_DIM + q * 8;

    f32x4 aL0 = {0,0,0,0}, aL1 = {0,0,0,0}, aR0 = {0,0,0,0}, aR1 = {0,0,0,0};
#pragma unroll
    for (int ks = 0; ks < 8; ks++) {            // k = m, 8 steps of 32
        f32x4 b0 = *(const f32x4*)(bsrc + ks * 32);
        f32x4 b1 = *(const f32x4*)(bsrc + ks * 32 + 4);
        f16x8 bf;
#pragma unroll
        for (int u = 0; u < 4; u++) { bf[u] = (f16)b0[u]; bf[4 + u] = (f16)b1[u]; }
        const f16* a0 = wt_l + li * M_DIM + ks * 32 + q * 8;
        const f16* a1 = wt_r + li * M_DIM + ks * 32 + q * 8;
        f16x8 al0 = *(const f16x8*)(a0);
        f16x8 al1 = *(const f16x8*)(a0 + 16 * M_DIM);
        f16x8 ar0 = *(const f16x8*)(a1);
        f16x8 ar1 = *(const f16x8*)(a1 + 16 * M_DIM);
        aL0 = __builtin_amdgcn_mfma_f32_16x16x32_f16(al0, bf, aL0, 0, 0, 0);
        aL1 = __builtin_amdgcn_mfma_f32_16x16x32_f16(al1, bf, aL1, 0, 0, 0);
        aR0 = __builtin_amdgcn_mfma_f32_16x16x32_f16(ar0, bf, aR0, 0, 0, 0);
        aR1 = __builtin_amdgcn_mfma_f32_16x16x32_f16(ar1, bf, aR1, 0, 0, 0);
    }
    // D: row = c = mt*16 + q*4 + reg ; col = s_col
#pragma unroll
    for (int reg = 0; reg < 4; reg++) {
        int c0 = q * 4 + reg;
        left_t [(r * C_DIM + c0) * S_DIM + s_col]      = (f16)aL0[reg];
        left_t [(r * C_DIM + c0 + 16) * S_DIM + s_col] = (f16)aL1[reg];
        right_t[(r * C_DIM + c0) * S_DIM + s_col]      = (f16)aR0[reg];
        right_t[(r * C_DIM + c0 + 16) * S_DIM + s_col] = (f16)aR1[reg];
    }
}

// ---------------------------------------------------------------------------
// main: per block: 8 r x 4 t pairs.
//  stage1: outer[(rc),(te)] = sum_s left_t[rc][s]*right_t[te][s]  (256x128x128)
//          -> f16 into 64KiB LDS as outer[p][k2], p = r_l*4+t_l, k2 = c*32+e,
//          XOR-swizzled at 16B-chunk granularity (bank spread; bijective per row).
//  stage2: out[p][cz] = sum_k2 outer[p][k2] * W[k2][cz]  ([32x1024]@[1024x128])
// ---------------------------------------------------------------------------
#define RT 8
#define TT 4

__device__ __forceinline__ int outer_off(int p, int k2) {
    int chunk = k2 >> 3;                                  // 16B chunk in row, 0..127
    int sw = chunk ^ ((chunk >> 3) & 7) ^ (p & 7);        // bank-spread swizzle
    return (p << 11) + (sw << 4) + ((k2 & 7) << 1);       // byte offset
}

__global__ __launch_bounds__(512, 2)
void main_kernel(const f16* __restrict__ left_t, const f16* __restrict__ right_t,
                 const f16* __restrict__ wt_o, float* __restrict__ out) {
    __shared__ uint4 lds_buf[4096];                       // 64 KiB
    char* lds = (char*)lds_buf;

    int bid = blockIdx.x;        // grid 2048 = 32 br * 64 bt
    int br = bid >> 6;           // 0..31  (R/RT)
    int bt = bid & 63;           // 0..63  (R/TT)
    int rc0 = br << 8;           // base rc row (br*256)
    int te0 = bt << 7;           // base te row (bt*128)
    int tid = threadIdx.x;
    int w = tid >> 6, lane = tid & 63, q = lane >> 4, li = lane & 15;

    // ---- stage 1 ---- wave grid 4(wm) x 2(wn): 4 Mt x 4 Nt tiles per wave
    int wm = w & 3, wn = w >> 2;
    f16x8 afr[4][4];             // cached A fragments: 4 Mt x 4 ksteps
#pragma unroll
    for (int i = 0; i < 4; i++) {
        const f16* ap = left_t + (rc0 + (4 * wm + i) * 16 + li) * S_DIM + q * 8;
#pragma unroll
        for (int ks = 0; ks < 4; ks++) afr[i][ks] = *(const f16x8*)(ap + ks * 32);
    }
#pragma unroll
    for (int j = 0; j < 4; j++) {
        int nt = 4 * wn + j;
        int te_l = nt * 16 + li;
        const f16* bp = right_t + (te0 + te_l) * S_DIM + q * 8;
        f16x8 bfr[4];
#pragma unroll
        for (int ks = 0; ks < 4; ks++) bfr[ks] = *(const f16x8*)(bp + ks * 32);
        int t_l = te_l >> 5, e = te_l & 31;
#pragma unroll
        for (int i = 0; i < 4; i++) {
            f32x4 acc = {0,0,0,0};
#pragma unroll
            for (int ks = 0; ks < 4; ks++)
                acc = __builtin_amdgcn_mfma_f32_16x16x32_f16(afr[i][ks], bfr[ks], acc, 0, 0, 0);
            int mt = 4 * wm + i;
            int p = (mt >> 1) * TT + t_l;          // tile lies in one r_l = mt>>1
            int cbase = (mt & 1) * 16 + q * 4;     // c = cbase + reg
#pragma unroll
            for (int reg = 0; reg < 4; reg++) {
                int k2 = (cbase + reg) * 32 + e;
                *(f16*)(lds + outer_off(p, k2)) = (f16)acc[reg];
            }
        }
    }
    __syncthreads();

    // ---- stage 2 ---- wave w -> cz tile w ; both 16-pair M2 tiles
    int cz0 = w << 4;
    f32x4 acc2[2] = {{0,0,0,0},{0,0,0,0}};
    const f16* wp = wt_o + (cz0 + li) * K2_DIM + q * 8;
#pragma unroll 4
    for (int ks2 = 0; ks2 < 32; ks2++) {
        f16x8 wf = *(const f16x8*)(wp + ks2 * 32);
        int k2b = ks2 * 32 + q * 8;               // 16B-aligned chunk in LDS row
        f16x8 a20 = *(const f16x8*)(lds + outer_off(li, k2b));
        f16x8 a21 = *(const f16x8*)(lds + outer_off(16 + li, k2b));
        acc2[0] = __builtin_amdgcn_mfma_f32_16x16x32_f16(a20, wf, acc2[0], 0, 0, 0);
        acc2[1] = __builtin_amdgcn_mfma_f32_16x16x32_f16(a21, wf, acc2[1], 0, 0, 0);
    }
    // D: row = p = m2*16 + q*4 + reg ; col = cz0 + li
    int r0 = br * RT, t0 = bt * TT;
#pragma unroll
    for (int m2 = 0; m2 < 2; m2++) {
#pragma unroll
        for (int reg = 0; reg < 4; reg++) {
            int p = m2 * 16 + q * 4 + reg;
            int rl = p >> 2, tl = p & 3;
            out[((((r0 + rl) << 8) + t0 + tl) << 7) + cz0 + li] = acc2[m2][reg];
        }
    }
}

// ---------------------------------------------------------------------------
extern "C" void kernel_launch(void* const* d_in, const int* in_sizes, int n_in,
                              void* d_out, int out_size, void* d_ws, size_t ws_size,
                              hipStream_t stream) {
    const float* msa = (const float*)d_in[0];
    const float* lw  = (const float*)d_in[1];
    const float* rw  = (const float*)d_in[2];
    const float* ow  = (const float*)d_in[3];
    char* ws = (char*)d_ws;
    // workspace layout (4.53 MB total)
    f16* left_t  = (f16*)(ws);                                   // 2 MB
    f16* right_t = (f16*)(ws + (size_t)2 * 1024 * 1024);         // 2 MB
    f16* wt_o    = (f16*)(ws + (size_t)4 * 1024 * 1024);         // 256 KB
    f16* wt_l    = (f16*)(ws + (size_t)4 * 1024 * 1024 + 262144);        // 16 KB
    f16* wt_r    = (f16*)(ws + (size_t)4 * 1024 * 1024 + 262144 + 16384);// 16 KB
    float* out   = (float*)d_out;

    prep_kernel<<<dim3(256), dim3(256), 0, stream>>>(lw, rw, ow, wt_l, wt_r, wt_o);
    proj_kernel<<<dim3(512), dim3(256), 0, stream>>>(msa, wt_l, wt_r, left_t, right_t);
    main_kernel<<<dim3(2048), dim3(512), 0, stream>>>(left_t, right_t, wt_o, out);
}

// Round 2
// 208.469 us; speedup vs baseline: 1.0257x; 1.0257x over previous
//
#include <hip/hip_runtime.h>
#include <stdint.h>

// Dims: msa[1,S,R,M] fp32 ; left_w/right_w[M,C] ; out_w[C*C,CZ] ; out[1,R,R,CZ] fp32
#define S_DIM 128
#define R_DIM 256
#define M_DIM 256
#define C_DIM 32
#define CZ_DIM 128
#define K2_DIM 1024  // C*C

typedef _Float16 f16;
typedef _Float16 f16x4 __attribute__((ext_vector_type(4)));
typedef _Float16 f16x8 __attribute__((ext_vector_type(8)));
typedef float f32x4 __attribute__((ext_vector_type(4)));

// LDS outer tile: 32 rows (pairs) x 1024 f16, row pitch 2112 B (2048+64:
// shifts bank phase by 16 per row so stage2's fixed-k2-column b128 reads
// spread over all 32 banks). Within-row layout: k2' = e*32 + c, stored at
// addr4 slot pos4(e,c>>1) = e*16 + ((c>>1) ^ (2*(e&7)))  (bank-spread XOR).
// wt_o is stored with the IDENTICAL slot mapping so A- and B-fragments of
// stage2 carry the same k-permutation (MFMA only needs pairwise k match).
#define ROWB 2112

__device__ __forceinline__ int k2off16(int ks2, int q) {
    // f16 index of the 16B block holding (e=ks2, c=q*8..q*8+7) after swizzle
    return ks2 * 32 + 8 * (q ^ ((ks2 >> 1) & 3));
}

// ---------------------------------------------------------------------------
// prep: weights -> f16. wt_l/wt_r[c][m]; wt_o[cz][swizzled k2'].
// ---------------------------------------------------------------------------
__global__ void prep_kernel(const float* __restrict__ lw, const float* __restrict__ rw,
                            const float* __restrict__ ow,
                            f16* __restrict__ wt_l, f16* __restrict__ wt_r,
                            f16* __restrict__ wt_o) {
    int idx = blockIdx.x * blockDim.x + threadIdx.x;
    int stride = gridDim.x * blockDim.x;
    for (int i = idx; i < CZ_DIM * K2_DIM; i += stride) {
        int cz = i >> 10, k2 = i & 1023;
        int c = k2 >> 5, e = k2 & 31;
        int slot = (e * 16 + ((c >> 1) ^ (2 * (e & 7)))) * 2 + (c & 1);
        wt_o[cz * K2_DIM + slot] = (f16)ow[k2 * CZ_DIM + cz];
    }
    for (int i = idx; i < C_DIM * M_DIM; i += stride) {
        int c = i >> 8, m = i & 255;
        wt_l[i] = (f16)lw[m * C_DIM + c];
        wt_r[i] = (f16)rw[m * C_DIM + c];
    }
}

// ---------------------------------------------------------------------------
// proj: per block (r, s-half): D = wt(32 c x 256 m) @ msa_r^T (256 m x 64 s).
// All 16 msa loads prefetched up front (128 HBM lines in flight per CU).
// ---------------------------------------------------------------------------
__global__ __launch_bounds__(256, 4)
void proj_kernel(const float* __restrict__ msa, const f16* __restrict__ wt_l,
                 const f16* __restrict__ wt_r,
                 f16* __restrict__ left_t, f16* __restrict__ right_t) {
    int bid = blockIdx.x;            // 512 = 256 r * 2 s-halves
    int r  = bid >> 1;
    int s0 = (bid & 1) << 6;         // 0 or 64
    int tid = threadIdx.x;
    int w = tid >> 6;                // wave 0..3 -> 16-wide s subtile
    int lane = tid & 63;
    int q = lane >> 4, li = lane & 15;

    int s_col = s0 + w * 16 + li;    // this lane's s (MFMA n index)
    const f32x4* bp = (const f32x4*)(msa + ((size_t)s_col * R_DIM + r) * M_DIM + q * 8);

    // prefetch the whole 1KB-per-(s,r) strip: 16 x f32x4 in flight
    f32x4 b[16];
#pragma unroll
    for (int ks = 0; ks < 8; ks++) { b[2 * ks] = bp[ks * 8]; b[2 * ks + 1] = bp[ks * 8 + 1]; }

    f32x4 aL0 = {0,0,0,0}, aL1 = {0,0,0,0}, aR0 = {0,0,0,0}, aR1 = {0,0,0,0};
#pragma unroll
    for (int ks = 0; ks < 8; ks++) {            // k = m, 8 steps of 32
        f16x8 bf;
#pragma unroll
        for (int u = 0; u < 4; u++) { bf[u] = (f16)b[2*ks][u]; bf[4 + u] = (f16)b[2*ks+1][u]; }
        const f16* a0 = wt_l + li * M_DIM + ks * 32 + q * 8;
        const f16* a1 = wt_r + li * M_DIM + ks * 32 + q * 8;
        f16x8 al0 = *(const f16x8*)(a0);
        f16x8 al1 = *(const f16x8*)(a0 + 16 * M_DIM);
        f16x8 ar0 = *(const f16x8*)(a1);
        f16x8 ar1 = *(const f16x8*)(a1 + 16 * M_DIM);
        aL0 = __builtin_amdgcn_mfma_f32_16x16x32_f16(al0, bf, aL0, 0, 0, 0);
        aL1 = __builtin_amdgcn_mfma_f32_16x16x32_f16(al1, bf, aL1, 0, 0, 0);
        aR0 = __builtin_amdgcn_mfma_f32_16x16x32_f16(ar0, bf, aR0, 0, 0, 0);
        aR1 = __builtin_amdgcn_mfma_f32_16x16x32_f16(ar1, bf, aR1, 0, 0, 0);
    }
    // D: row = c = mt*16 + q*4 + reg ; col = s_col
#pragma unroll
    for (int reg = 0; reg < 4; reg++) {
        int c0 = q * 4 + reg;
        left_t [(r * C_DIM + c0) * S_DIM + s_col]      = (f16)aL0[reg];
        left_t [(r * C_DIM + c0 + 16) * S_DIM + s_col] = (f16)aL1[reg];
        right_t[(r * C_DIM + c0) * S_DIM + s_col]      = (f16)aR0[reg];
        right_t[(r * C_DIM + c0 + 16) * S_DIM + s_col] = (f16)aR1[reg];
    }
}

// ---------------------------------------------------------------------------
// main: per block: 8 r x 4 t pairs (32 pairs).
//  stage1: outer -> f16 into 66KB LDS (b64 swizzled writes, volume-minimal)
//  stage2: out[p][cz] = sum_k2 outer[p][k2'] * W[k2'][cz], W-group prefetch
// ---------------------------------------------------------------------------
#define RT 8
#define TT 4

__global__ __launch_bounds__(512, 4)
void main_kernel(const f16* __restrict__ left_t, const f16* __restrict__ right_t,
                 const f16* __restrict__ wt_o, float* __restrict__ out) {
    __shared__ __align__(16) char lds[32 * ROWB];       // 66 KiB

    int bid = blockIdx.x;        // grid 2048 = 32 br * 64 bt
    int br = bid >> 6;           // 0..31  (R/RT)
    int bt = bid & 63;           // 0..63  (R/TT)
    int rc0 = br << 8;           // base rc row (br*256)
    int te0 = bt << 7;           // base te row (bt*128)
    int tid = threadIdx.x;
    int w = tid >> 6, lane = tid & 63, q = lane >> 4, li = lane & 15;

    // ---- stage 1 ---- wave grid 4(wm) x 2(wn): 4 Mt x 4 Nt tiles per wave
    int wm = w & 3, wn = w >> 2;
    f16x8 afr[4][4];             // cached A fragments: 4 Mt x 4 ksteps
#pragma unroll
    for (int i = 0; i < 4; i++) {
        const f16* ap = left_t + (rc0 + (4 * wm + i) * 16 + li) * S_DIM + q * 8;
#pragma unroll
        for (int ks = 0; ks < 4; ks++) afr[i][ks] = *(const f16x8*)(ap + ks * 32);
    }
#pragma unroll
    for (int j = 0; j < 4; j++) {
        int nt = 4 * wn + j;
        int te_l = nt * 16 + li;
        const f16* bpr = right_t + (te0 + te_l) * S_DIM + q * 8;
        f16x8 bfr[4];
#pragma unroll
        for (int ks = 0; ks < 4; ks++) bfr[ks] = *(const f16x8*)(bpr + ks * 32);
        int t_l = te_l >> 5, e = te_l & 31;
#pragma unroll
        for (int i = 0; i < 4; i++) {
            f32x4 acc = {0,0,0,0};
#pragma unroll
            for (int ks = 0; ks < 4; ks++)
                acc = __builtin_amdgcn_mfma_f32_16x16x32_f16(afr[i][ks], bfr[ks], acc, 0, 0, 0);
            int mt = 4 * wm + i;
            int p = (mt >> 1) * TT + t_l;              // pair row 0..31
            int ch = 8 * (mt & 1) + 2 * q;             // (c0 = (mt&1)*16+q*4) >> 1
            f16x4 h = {(f16)acc[0], (f16)acc[1], (f16)acc[2], (f16)acc[3]};
            *(f16x4*)(lds + p * ROWB + (e * 16 + (ch ^ (2 * (e & 7)))) * 4) = h;
        }
    }

    // ---- stage 2 ---- wave w -> cz tile w ; both 16-pair M2 tiles
    int cz0 = w << 4;
    const f16* wrow = wt_o + (cz0 + li) * K2_DIM;
    const char* arow0 = lds + li * ROWB;
    const char* arow1 = lds + (16 + li) * ROWB;

    // prefetch W group 0 BEFORE the barrier (independent of LDS)
    f16x8 wf[4];
#pragma unroll
    for (int u = 0; u < 4; u++) wf[u] = *(const f16x8*)(wrow + k2off16(u, q));

    __syncthreads();

    f32x4 acc2[2] = {{0,0,0,0},{0,0,0,0}};
#pragma unroll
    for (int g = 0; g < 8; g++) {
        f16x8 a0[4], a1[4];
#pragma unroll
        for (int u = 0; u < 4; u++) {
            int o = k2off16(g * 4 + u, q) * 2;         // byte offset in LDS row
            a0[u] = *(const f16x8*)(arow0 + o);
            a1[u] = *(const f16x8*)(arow1 + o);
        }
        f16x8 wnx[4];
        if (g < 7) {
#pragma unroll
            for (int u = 0; u < 4; u++) wnx[u] = *(const f16x8*)(wrow + k2off16(g * 4 + 4 + u, q));
        }
#pragma unroll
        for (int u = 0; u < 4; u++) {
            acc2[0] = __builtin_amdgcn_mfma_f32_16x16x32_f16(a0[u], wf[u], acc2[0], 0, 0, 0);
            acc2[1] = __builtin_amdgcn_mfma_f32_16x16x32_f16(a1[u], wf[u], acc2[1], 0, 0, 0);
        }
        if (g < 7) {
#pragma unroll
            for (int u = 0; u < 4; u++) wf[u] = wnx[u];
        }
    }

    // D: row = p = m2*16 + q*4 + reg ; col = cz0 + li
    int r0 = br * RT, t0 = bt * TT;
#pragma unroll
    for (int m2 = 0; m2 < 2; m2++) {
#pragma unroll
        for (int reg = 0; reg < 4; reg++) {
            int p = m2 * 16 + q * 4 + reg;
            int rl = p >> 2, tl = p & 3;
            out[((((r0 + rl) << 8) + t0 + tl) << 7) + cz0 + li] = acc2[m2][reg];
        }
    }
}

// ---------------------------------------------------------------------------
extern "C" void kernel_launch(void* const* d_in, const int* in_sizes, int n_in,
                              void* d_out, int out_size, void* d_ws, size_t ws_size,
                              hipStream_t stream) {
    const float* msa = (const float*)d_in[0];
    const float* lw  = (const float*)d_in[1];
    const float* rw  = (const float*)d_in[2];
    const float* ow  = (const float*)d_in[3];
    char* ws = (char*)d_ws;
    f16* left_t  = (f16*)(ws);                                   // 2 MB
    f16* right_t = (f16*)(ws + (size_t)2 * 1024 * 1024);         // 2 MB
    f16* wt_o    = (f16*)(ws + (size_t)4 * 1024 * 1024);         // 256 KB
    f16* wt_l    = (f16*)(ws + (size_t)4 * 1024 * 1024 + 262144);        // 16 KB
    f16* wt_r    = (f16*)(ws + (size_t)4 * 1024 * 1024 + 262144 + 16384);// 16 KB
    float* out   = (float*)d_out;

    prep_kernel<<<dim3(256), dim3(256), 0, stream>>>(lw, rw, ow, wt_l, wt_r, wt_o);
    proj_kernel<<<dim3(512), dim3(256), 0, stream>>>(msa, wt_l, wt_r, left_t, right_t);
    main_kernel<<<dim3(2048), dim3(512), 0, stream>>>(left_t, right_t, wt_o, out);
}

// Round 4
// 161.980 us; speedup vs baseline: 1.3201x; 1.2870x over previous
//
#include <hip/hip_runtime.h>
#include <stdint.h>

// Dims: msa[1,S,R,M] fp32 ; left_w/right_w[M,C] ; out_w[C*C,CZ] ; out[1,R,R,CZ] fp32
#define S_DIM 128
#define R_DIM 256
#define M_DIM 256
#define C_DIM 32
#define CZ_DIM 128
#define K2_DIM 1024  // C*C

typedef _Float16 f16;
typedef _Float16 f16x8 __attribute__((ext_vector_type(8)));
typedef float f32x4 __attribute__((ext_vector_type(4)));
typedef float f32x16 __attribute__((ext_vector_type(16)));

// ---------------------------------------------------------------------------
// prep: weights -> f16. wt_l/wt_r[c][m]; wt_o[cz][k2] (plain transpose of ow,
// coalesced writes).
// ---------------------------------------------------------------------------
__global__ void prep_kernel(const float* __restrict__ lw, const float* __restrict__ rw,
                            const float* __restrict__ ow,
                            f16* __restrict__ wt_l, f16* __restrict__ wt_r,
                            f16* __restrict__ wt_o) {
    int idx = blockIdx.x * blockDim.x + threadIdx.x;
    int stride = gridDim.x * blockDim.x;
    for (int i = idx; i < CZ_DIM * K2_DIM; i += stride) {
        int cz = i >> 10, k2 = i & 1023;
        wt_o[i] = (f16)ow[k2 * CZ_DIM + cz];
    }
    for (int i = idx; i < C_DIM * M_DIM; i += stride) {
        int c = i >> 8, m = i & 255;
        wt_l[i] = (f16)lw[m * C_DIM + c];
        wt_r[i] = (f16)rw[m * C_DIM + c];
    }
}

// ---------------------------------------------------------------------------
// proj (correctness-proven): per block (r, s-half):
// D = wt(32 c x 256 m) @ msa_r^T (256 m x 64 s); writes left_t/right_t[(rc)][s].
// ---------------------------------------------------------------------------
__global__ __launch_bounds__(256, 4)
void proj_kernel(const float* __restrict__ msa, const f16* __restrict__ wt_l,
                 const f16* __restrict__ wt_r,
                 f16* __restrict__ left_t, f16* __restrict__ right_t) {
    int bid = blockIdx.x;            // 512 = 256 r * 2 s-halves
    int r  = bid >> 1;
    int s0 = (bid & 1) << 6;
    int tid = threadIdx.x;
    int w = tid >> 6;
    int lane = tid & 63;
    int q = lane >> 4, li = lane & 15;

    int s_col = s0 + w * 16 + li;
    const f32x4* bp = (const f32x4*)(msa + ((size_t)s_col * R_DIM + r) * M_DIM + q * 8);

    f32x4 b[16];
#pragma unroll
    for (int ks = 0; ks < 8; ks++) { b[2 * ks] = bp[ks * 8]; b[2 * ks + 1] = bp[ks * 8 + 1]; }

    f32x4 aL0 = {0,0,0,0}, aL1 = {0,0,0,0}, aR0 = {0,0,0,0}, aR1 = {0,0,0,0};
#pragma unroll
    for (int ks = 0; ks < 8; ks++) {
        f16x8 bf;
#pragma unroll
        for (int u = 0; u < 4; u++) { bf[u] = (f16)b[2*ks][u]; bf[4 + u] = (f16)b[2*ks+1][u]; }
        const f16* a0 = wt_l + li * M_DIM + ks * 32 + q * 8;
        const f16* a1 = wt_r + li * M_DIM + ks * 32 + q * 8;
        f16x8 al0 = *(const f16x8*)(a0);
        f16x8 al1 = *(const f16x8*)(a0 + 16 * M_DIM);
        f16x8 ar0 = *(const f16x8*)(a1);
        f16x8 ar1 = *(const f16x8*)(a1 + 16 * M_DIM);
        aL0 = __builtin_amdgcn_mfma_f32_16x16x32_f16(al0, bf, aL0, 0, 0, 0);
        aL1 = __builtin_amdgcn_mfma_f32_16x16x32_f16(al1, bf, aL1, 0, 0, 0);
        aR0 = __builtin_amdgcn_mfma_f32_16x16x32_f16(ar0, bf, aR0, 0, 0, 0);
        aR1 = __builtin_amdgcn_mfma_f32_16x16x32_f16(ar1, bf, aR1, 0, 0, 0);
    }
#pragma unroll
    for (int reg = 0; reg < 4; reg++) {
        int c0 = q * 4 + reg;
        left_t [(r * C_DIM + c0) * S_DIM + s_col]      = (f16)aL0[reg];
        left_t [(r * C_DIM + c0 + 16) * S_DIM + s_col] = (f16)aL1[reg];
        right_t[(r * C_DIM + c0) * S_DIM + s_col]      = (f16)aR0[reg];
        right_t[(r * C_DIM + c0 + 16) * S_DIM + s_col] = (f16)aR1[reg];
    }
}

// ---------------------------------------------------------------------------
// outer_kernel: per block: D[128 rc][128 te] = A[128][128s] * B[128][128s]^T
// A/B staged once into 64KB LDS (XOR chunk swizzle phys_ch = ch ^ (row&15)).
// 8 waves x (2 x 32x32 tiles). Writes outer[p][k2] f16 (k2 = c*32+e).
// ---------------------------------------------------------------------------
__global__ __launch_bounds__(512, 4)
void outer_kernel(const f16* __restrict__ left_t, const f16* __restrict__ right_t,
                  f16* __restrict__ outer) {
    __shared__ f16 As[128 * 128];
    __shared__ f16 Bs[128 * 128];

    int bid = blockIdx.x;            // 4096 = 64 bi * 64 bj
    int bi = bid >> 6, bj = bid & 63;
    int tid = threadIdx.x;
    int w = tid >> 6, lane = tid & 63, q5 = lane >> 5;

    const f16* Ag = left_t  + (size_t)bi * 16384;   // 128 rows x 128 s
    const f16* Bg = right_t + (size_t)bj * 16384;

    // ---- stage A and B (32KB each): 4 it x 512 thr x 16B covers 128x128 ----
#pragma unroll
    for (int it = 0; it < 4; it++) {
        int G = it * 512 + tid;                     // 16B chunk id, 0..2047
        int row = G >> 4, ch = G & 15;
        f16x8 va = *(const f16x8*)(Ag + G * 8);
        f16x8 vb = *(const f16x8*)(Bg + G * 8);
        int off = row * 128 + ((ch ^ (row & 15)) << 3);
        *(f16x8*)(As + off) = va;
        *(f16x8*)(Bs + off) = vb;
    }
    __syncthreads();

    // ---- compute: wave tile = 64 rows x 32 cols ----
    int wm = w >> 2, wn = w & 3;
    int m0 = wm * 64 + (lane & 31);
    int nrow = wn * 32 + (lane & 31);
    int lx = lane & 15;

    f32x16 acc[2] = {};
#pragma unroll
    for (int ks = 0; ks < 8; ks++) {
        int ch = 2 * ks + q5;
        int sw = ((ch ^ lx) << 3);
        f16x8 bfr = *(const f16x8*)(Bs + nrow * 128 + sw);
#pragma unroll
        for (int i = 0; i < 2; i++) {
            f16x8 afr = *(const f16x8*)(As + (m0 + i * 32) * 128 + sw);
            acc[i] = __builtin_amdgcn_mfma_f32_32x32x16_f16(afr, bfr, acc[i], 0, 0, 0);
        }
    }

    // ---- store: tile (wm*2+i, wn) = pair (r0+wm*2+i, t0+wn), 32c x 32e ----
    int r0 = bi * 4, t0 = bj * 4;
    int e = lane & 31;
#pragma unroll
    for (int i = 0; i < 2; i++) {
        int p = (r0 + wm * 2 + i) * R_DIM + (t0 + wn);
        f16* orow = outer + (size_t)p * K2_DIM;
#pragma unroll
        for (int reg = 0; reg < 16; reg++) {
            int c = (reg & 3) + 8 * (reg >> 2) + 4 * q5;
            orow[c * 32 + e] = (f16)acc[i][reg];
        }
    }
}

// ---------------------------------------------------------------------------
// out_kernel: out[p][cz] = sum_k2 outer[p][k2] * wt_o[cz][k2].
// M=65536, K=1024, N=128. Block: 128 p-rows, k in 16 chunks of 64,
// double-buffered LDS. FIXED R3 BUG: stage ALL 128 rows of A and W per chunk
// (rows srow and srow+64 per thread; (srow+64)&7 == srow&7 keeps swizzle).
// ---------------------------------------------------------------------------
__global__ __launch_bounds__(512, 4)
void out_kernel(const f16* __restrict__ outer, const f16* __restrict__ wt_o,
                float* __restrict__ out) {
    __shared__ f16 Ab[2][128 * 64];
    __shared__ f16 Wb[2][128 * 64];

    int tid = threadIdx.x;
    int w = tid >> 6, lane = tid & 63, q5 = lane >> 5;
    size_t p0 = (size_t)blockIdx.x * 128;

    int srow = tid >> 3, sch = tid & 7;             // row 0..63, 16B chunk 0..7
    const f16* gA0 = outer + (p0 + srow) * K2_DIM + sch * 8;
    const f16* gA1 = outer + (p0 + srow + 64) * K2_DIM + sch * 8;
    const f16* gW0 = wt_o + (size_t)srow * K2_DIM + sch * 8;
    const f16* gW1 = wt_o + (size_t)(srow + 64) * K2_DIM + sch * 8;
    int soff0 = srow * 64 + ((sch ^ (srow & 7)) << 3);
    int soff1 = soff0 + 64 * 64;

    // preload chunk 0
    f16x8 ra0 = *(const f16x8*)(gA0);
    f16x8 ra1 = *(const f16x8*)(gA1);
    f16x8 rw0 = *(const f16x8*)(gW0);
    f16x8 rw1 = *(const f16x8*)(gW1);
    *(f16x8*)(&Ab[0][soff0]) = ra0;
    *(f16x8*)(&Ab[0][soff1]) = ra1;
    *(f16x8*)(&Wb[0][soff0]) = rw0;
    *(f16x8*)(&Wb[0][soff1]) = rw1;
    __syncthreads();

    int wm = w >> 2, wn = w & 3;
    int m0 = wm * 64 + (lane & 31);
    int nrow = wn * 32 + (lane & 31);
    int lx = lane & 7;

    f32x16 acc[2] = {};
#pragma unroll 1
    for (int g = 0; g < 16; g++) {
        int cur = g & 1;
        if (g < 15) {                               // issue next-chunk loads early
            ra0 = *(const f16x8*)(gA0 + (g + 1) * 64);
            ra1 = *(const f16x8*)(gA1 + (g + 1) * 64);
            rw0 = *(const f16x8*)(gW0 + (g + 1) * 64);
            rw1 = *(const f16x8*)(gW1 + (g + 1) * 64);
        }
        const f16* Ac = Ab[cur];
        const f16* Wc = Wb[cur];
#pragma unroll
        for (int ksl = 0; ksl < 4; ksl++) {
            int ch = 2 * ksl + q5;
            int sw = ((ch ^ lx) << 3);
            f16x8 wf = *(const f16x8*)(Wc + nrow * 64 + sw);
#pragma unroll
            for (int i = 0; i < 2; i++) {
                f16x8 af = *(const f16x8*)(Ac + (m0 + i * 32) * 64 + sw);
                acc[i] = __builtin_amdgcn_mfma_f32_32x32x16_f16(af, wf, acc[i], 0, 0, 0);
            }
        }
        __syncthreads();
        if (g < 15) {
            *(f16x8*)(&Ab[cur ^ 1][soff0]) = ra0;
            *(f16x8*)(&Ab[cur ^ 1][soff1]) = ra1;
            *(f16x8*)(&Wb[cur ^ 1][soff0]) = rw0;
            *(f16x8*)(&Wb[cur ^ 1][soff1]) = rw1;
        }
        __syncthreads();
    }

    // store: D rows = p, cols = cz
    int cz = wn * 32 + (lane & 31);
#pragma unroll
    for (int i = 0; i < 2; i++) {
#pragma unroll
        for (int reg = 0; reg < 16; reg++) {
            int prow = wm * 64 + i * 32 + (reg & 3) + 8 * (reg >> 2) + 4 * q5;
            out[(p0 + prow) * CZ_DIM + cz] = acc[i][reg];
        }
    }
}

// ---------------------------------------------------------------------------
extern "C" void kernel_launch(void* const* d_in, const int* in_sizes, int n_in,
                              void* d_out, int out_size, void* d_ws, size_t ws_size,
                              hipStream_t stream) {
    const float* msa = (const float*)d_in[0];
    const float* lw  = (const float*)d_in[1];
    const float* rw  = (const float*)d_in[2];
    const float* ow  = (const float*)d_in[3];
    char* ws = (char*)d_ws;
    // workspace layout: 8MB header + 128MB outer = 136MB
    f16* left_t  = (f16*)(ws);                                   // 2 MB
    f16* right_t = (f16*)(ws + (size_t)2 * 1024 * 1024);         // 2 MB
    f16* wt_o    = (f16*)(ws + (size_t)4 * 1024 * 1024);         // 256 KB
    f16* wt_l    = (f16*)(ws + (size_t)4 * 1024 * 1024 + 262144);        // 16 KB
    f16* wt_r    = (f16*)(ws + (size_t)4 * 1024 * 1024 + 262144 + 16384);// 16 KB
    f16* outer   = (f16*)(ws + (size_t)8 * 1024 * 1024);         // 128 MB
    float* out   = (float*)d_out;

    prep_kernel<<<dim3(256), dim3(256), 0, stream>>>(lw, rw, ow, wt_l, wt_r, wt_o);
    proj_kernel<<<dim3(512), dim3(256), 0, stream>>>(msa, wt_l, wt_r, left_t, right_t);
    outer_kernel<<<dim3(4096), dim3(512), 0, stream>>>(left_t, right_t, outer);
    out_kernel<<<dim3(512), dim3(512), 0, stream>>>(outer, wt_o, out);
}